// Round 4
// baseline (722.948 us; speedup 1.0000x reference)
//
#include <hip/hip_runtime.h>
#include <cstdint>
#include <cstddef>

#define T_STEPS 64
#define F_INP 5
#define LOG2E 1.44269504088896340736f

typedef _Float16 f16x8 __attribute__((ext_vector_type(8)));
typedef float f32x4 __attribute__((ext_vector_type(4)));

__device__ __forceinline__ float leaky(float x, float s){ return x>0.f? x : s*x; }
__device__ __forceinline__ float rcpf(float x){ return __builtin_amdgcn_rcpf(x); }
__device__ __forceinline__ float exp2fast(float x){ return __builtin_amdgcn_exp2f(x); }

#define MF(a,b,c) __builtin_amdgcn_mfma_f32_16x16x32_f16((a),(b),(c),0,0,0)

// ---------------- MFMA LSTM + fused GAT-prep epilogue.
// 32 nodes/block, 4 waves. Wave wq owns gate-columns [16wq,16wq+16) of all 4
// gates. Trans floor: 5 exp + 2 rcp per cell element = ~53% of SIMD cycles at
// 4 waves/SIMD -> occupancy is the lever, not issue order (round-3 lesson).
// Round-4: register diet to fit 5 waves/SIMD (budget 512/5 ~= 96-102):
//  - W_hh k=32..63 + W_ih/bias fragments streamed from LDS images (built in
//    prologue, pre-swizzled to MFMA frag layout, 1 ds_read_b128 each) -> -32 regs
//  - acc back to 16 regs (m sequential); soff/roff arrays -> inline XOR math
//  - final-step h collected in regs, written to f32 scratch OVERLAID on the
//    then-dead BH1 image after the loop barrier (keeps LDS at ~29.7KB)
// WATCH: if FETCH_SIZE balloons vs 64MB, the (256,5) budget spilled -> revert
// to (256,4). (256,8) is catastrophic: 32-reg budget, 8.9GB scratch traffic.
__global__ __launch_bounds__(256, 5) void lstm_mfma(
    const float* __restrict__ x, const float* __restrict__ W_ih,
    const float* __restrict__ W_hh, const float* __restrict__ b_ih,
    const float* __restrict__ b_hh, const float* __restrict__ vcomb,
    float2* __restrict__ asx, float* __restrict__ a_dst,
    float* __restrict__ denom, float* __restrict__ oacc, int N)
{
  __shared__ __align__(16) _Float16 Hs0[32][64];
  __shared__ __align__(16) _Float16 Hs1[32][64];
  __shared__ __align__(16) _Float16 Xs0[32][8];
  __shared__ __align__(16) _Float16 Xs1[32][8];
  __shared__ __align__(16) _Float16 Zero8[8];
  __shared__ __align__(16) _Float16 BH1[8192];  // [n][wq][lane][8] frags, k=32..63 (16KB)
  __shared__ __align__(16) _Float16 BXI[2048];  // [n][wq][l<16][8] x-gate frags (4KB)

  const int tid   = threadIdx.x;
  const int lane  = tid & 63;
  const int wq    = tid >> 6;      // 0..3 gate-col slice
  const int col16 = lane & 15;
  const int grp   = lane >> 4;
  const int base  = blockIdx.x * 32;

  // ---- Bh0: W_hh k=0..31 fragments kept in registers (16 VGPR).
  f16x8 Bh0[4];
  #pragma unroll
  for (int n=0;n<4;n++){
    const float sc = (n==2) ? 2.f*LOG2E : LOG2E;
    const int gate = n*64 + wq*16 + col16;
    const float* p = W_hh + gate*64 + grp*8;
    #pragma unroll
    for (int e=0;e<8;e++) Bh0[n][e] = (_Float16)(p[e]*sc);
  }

  // ---- BH1 image: 1024 fragment-slots (n,wq,l), each 8 f16.
  #pragma unroll
  for (int it=0; it<4; ++it){
    const int idx = it*256 + tid;
    const int n   = idx >> 8;
    const int wqi = (idx >> 6) & 3;
    const int l   = idx & 63;
    const float sc = (n==2) ? 2.f*LOG2E : LOG2E;
    const int gate = n*64 + wqi*16 + (l & 15);
    const float* p = W_hh + gate*64 + 32 + (l>>4)*8;
    f16x8 v;
    #pragma unroll
    for (int e=0;e<8;e++) v[e] = (_Float16)(p[e]*sc);
    *(f16x8*)&BH1[idx*8] = v;
  }
  // ---- BXI image: 256 slots (n,wq,l<16): W_ih cols + fused bias at e=5.
  {
    const int n   = tid >> 6;
    const int wqi = (tid >> 4) & 3;
    const int l   = tid & 15;
    const float sc = (n==2) ? 2.f*LOG2E : LOG2E;
    const int gate = n*64 + wqi*16 + l;
    f16x8 v = {0,0,0,0,0,0,0,0};
    #pragma unroll
    for (int e=0;e<5;e++) v[e] = (_Float16)(W_ih[gate*5+e]*sc);
    v[5] = (_Float16)((b_ih[gate]+b_hh[gate])*sc);
    *(f16x8*)&BXI[tid*8] = v;
  }

  // zero Hs0 (4 KB = 256 float4) + Zero8
  ((float4*)&Hs0[0][0])[tid] = float4{0.f,0.f,0.f,0.f};
  if (tid==0) ((float4*)Zero8)[0] = float4{0.f,0.f,0.f,0.f};

  // ---- distributed x staging: thread tid<160 owns (node=tid/5, elem=tid%5)
  const int  xn5  = tid/5, xe5 = tid - xn5*5;
  const bool xact = (tid < 160);
  const int  gxnode = base + xn5;
  const bool xlive  = xact && (gxnode < N);
  const float* xptr = x + (size_t)(xlive ? gxnode : 0)*(T_STEPS*F_INP) + xe5 + F_INP;
  if (xact){
    float v0 = xlive ? x[(size_t)gxnode*(T_STEPS*F_INP) + xe5] : 0.f;
    Xs0[xn5][xe5] = (_Float16)v0;
  }
  if (tid < 32){
    Xs0[tid][5]=(_Float16)1.f; Xs0[tid][6]=(_Float16)0.f; Xs0[tid][7]=(_Float16)0.f;
    Xs1[tid][5]=(_Float16)1.f; Xs1[tid][6]=(_Float16)0.f; Xs1[tid][7]=(_Float16)0.f;
  }

  // ---- loop-invariant addressing (element units; m-offsets via imm)
  const int sw    = (col16&7)<<3;
  const int roff0 = col16*64 + ((grp*8) ^ sw);   // A k=0..31, m=0
  const int roff1 = roff0 ^ 32;                  // A k=32..63
  const int xoff0 = col16*8;
  const int j     = wq*16 + col16;
  const int jg    = j ^ ((grp&1)<<5);            // store-swizzle base
  const int sb    = 4*grp*64;                    // store node base (m via imm)
  const _Float16* bh1p = BH1 + (wq*64 + lane)*8;
  const _Float16* bxip = (lane<16) ? (BXI + (wq*16 + lane)*8) : Zero8;
  const int bxstep = (lane<16) ? 512 : 0;        // per-gate stride (0 -> bcast zeros)

  float creg[2][4];
  float hreg[2][4];
  #pragma unroll
  for (int m=0;m<2;m++)
    #pragma unroll
    for (int r=0;r<4;r++) creg[m][r]=0.f;

  __syncthreads();

#define LSTM_STEP(HC, HN, XC, XN, XOFF, LAST) {                                \
    float xval = 0.f;                                                          \
    if (!(LAST) && xlive) xval = xptr[XOFF];                                   \
    f16x8 s10 = *(const f16x8*)(bh1p);                                         \
    f16x8 s11 = *(const f16x8*)(bh1p + 2048);                                  \
    f16x8 s12 = *(const f16x8*)(bh1p + 4096);                                  \
    f16x8 s13 = *(const f16x8*)(bh1p + 6144);                                  \
    f16x8 sx0 = *(const f16x8*)(bxip);                                         \
    f16x8 sx1 = *(const f16x8*)(bxip + bxstep);                                \
    f16x8 sx2 = *(const f16x8*)(bxip + 2*bxstep);                              \
    f16x8 sx3 = *(const f16x8*)(bxip + 2*bxstep + bxstep);                     \
    _Pragma("unroll")                                                          \
    for (int m=0;m<2;m++){                                                     \
      f16x8 a0 = *(const f16x8*)(&HC[0][0] + roff0 + m*1024);                  \
      f16x8 a1 = *(const f16x8*)(&HC[0][0] + roff1 + m*1024);                  \
      const _Float16* px = (grp==0) ? (&XC[0][0] + xoff0 + m*128) : Zero8;     \
      f16x8 ax = *(const f16x8*)px;                                            \
      f32x4 z4 = f32x4{0.f,0.f,0.f,0.f};                                       \
      f32x4 c0=z4, c1=z4, c2=z4, c3=z4;                                        \
      c0 = MF(a0, Bh0[0], c0); c1 = MF(a0, Bh0[1], c1);                        \
      c2 = MF(a0, Bh0[2], c2); c3 = MF(a0, Bh0[3], c3);                        \
      c0 = MF(a1, s10, c0);    c1 = MF(a1, s11, c1);                           \
      c2 = MF(a1, s12, c2);    c3 = MF(a1, s13, c3);                           \
      c0 = MF(ax, sx0, c0);    c1 = MF(ax, sx1, c1);                           \
      c2 = MF(ax, sx2, c2);    c3 = MF(ax, sx3, c3);                           \
      _Pragma("unroll")                                                        \
      for (int r=0;r<4;r++){                                                   \
        float e_i = exp2fast(-c0[r]);                                          \
        float e_f = exp2fast(-c1[r]);                                          \
        float zg2 = fminf(c2[r], 60.f);                                        \
        float e_g = exp2fast(zg2);                                             \
        float e_o = exp2fast(-c3[r]);                                          \
        float Ag = (1.f+e_i)*(1.f+e_g);                                        \
        float Bf = 1.f+e_f;                                                    \
        float rD = rcpf(Ag*Bf);                                                \
        float cn = (creg[m][r]*Ag + (e_g-1.f)*Bf)*rD;                          \
        creg[m][r] = cn;                                                       \
        float c2v = fminf(cn*(2.f*LOG2E), 120.f);                              \
        float e_c = exp2fast(c2v);                                             \
        float hv = (e_c-1.f)*rcpf((1.f+e_o)*(1.f+e_c));                        \
        if (LAST){                                                             \
          hreg[m][r] = hv;                                                     \
        } else {                                                               \
          (&HN[0][0])[sb + m*1024 + r*64 + (jg ^ (r<<3))] = (_Float16)hv;      \
        }                                                                      \
      }                                                                        \
    }                                                                          \
    if (!(LAST) && xact) XN[xn5][xe5] = (_Float16)xval;                        \
  }

  for (int tt=0; tt<T_STEPS/2; ++tt){
    LSTM_STEP(Hs0, Hs1, Xs0, Xs1, 0, false);
    __syncthreads();
    LSTM_STEP(Hs1, Hs0, Xs1, Xs0, F_INP, (tt==T_STEPS/2-1));
    __syncthreads();
    xptr += 2*F_INP;
  }
#undef LSTM_STEP

  // ---- final h (f32) into scratch overlaid on the now-dead BH1 image.
  // Loop-end barrier guarantees all waves finished their last BH1 reads.
  float* HfOv = (float*)BH1;   // needs 32*65*4 = 8320B <= 16384B
  #pragma unroll
  for (int m=0;m<2;m++)
    #pragma unroll
    for (int r=0;r<4;r++)
      HfOv[(16*m + 4*grp + r)*65 + j] = hreg[m][r];
  __syncthreads();

  // ---- fused GAT prep: 8 threads per node, dot h with vcomb.
  const int en = tid >> 3, es = tid & 7;
  const int gn2 = base + en;
  float as=0.f, ad=0.f, xf=0.f;
  #pragma unroll
  for (int q=0;q<8;q++){
    float hv = HfOv[en*65 + es*8 + q];
    as = fmaf(hv, vcomb[es*8+q],     as);
    ad = fmaf(hv, vcomb[64+es*8+q],  ad);
    xf = fmaf(hv, vcomb[128+es*8+q], xf);
  }
  #pragma unroll
  for (int off=1; off<8; off<<=1){
    as += __shfl_xor(as, off);
    ad += __shfl_xor(ad, off);
    xf += __shfl_xor(xf, off);
  }
  if (es==0 && gn2 < N){
    asx[gn2]   = float2{as, xf};
    a_dst[gn2] = ad;
    denom[gn2] = 0.f;
    oacc[gn2]  = 0.f;
  }
}

// ---------------- GAT setup (one 64-thread block), wave-parallel:
// mode detect via ballot; vcomb = gat_w^T {att_src, att_dst, fc_w};
// bias-dot scalar via shfl reduce.
__global__ void gat_setup(const int* __restrict__ ei,
                          const float* __restrict__ gat_w,
                          const float* __restrict__ att_src,
                          const float* __restrict__ att_dst,
                          const float* __restrict__ fc_w,
                          const float* __restrict__ gat_bias,
                          const float* __restrict__ fc_b,
                          float* __restrict__ vcomb,
                          unsigned* __restrict__ mode)
{
  int j = threadIdx.x;   // 0..63, one full wave
  unsigned long long nz = __ballot(ei[2*j+1] != 0);
  float bdp = gat_bias[j]*fc_w[j];
  #pragma unroll
  for (int off=32; off; off>>=1) bdp += __shfl_down(bdp, off);
  if (j==0){
    *mode = (nz==0ULL) ? 1u : 0u;
    vcomb[192] = bdp + fc_b[0];
  }
  float va=0.f, vd=0.f, vf=0.f;
  #pragma unroll 8
  for (int k=0;k<64;k++){
    float g = gat_w[k*64+j];
    va += att_src[k]*g;
    vd += att_dst[k]*g;
    vf += fc_w[k]*g;
  }
  vcomb[j]=va; vcomb[64+j]=vd; vcomb[128+j]=vf;
}

__device__ __forceinline__ void load_edge(const int* ei, unsigned mode,
                                          long long e, long long E,
                                          int& s, int& d)
{
  if (e>=E){ s=d=(int)(e-E); }
  else if (mode){
    const long long* e64 = (const long long*)ei;
    s=(int)e64[e]; d=(int)e64[E+e];
  } else {
    s=ei[e]; d=ei[E+e];
  }
}

// single pass: softmax normalization deferred to finalize.
// out[d] = (sum ew*xf_s)/(sum ew). asx packs {a_src, xfv} -> one 8B gather.
__global__ __launch_bounds__(256) void edge_pass(
    const int* __restrict__ ei, const unsigned* __restrict__ mode_p,
    const float2* __restrict__ asx, const float* __restrict__ a_dst,
    float* __restrict__ denom, float* __restrict__ oacc,
    long long E, long long total)
{
  long long e = (long long)blockIdx.x*256 + threadIdx.x;
  if (e>=total) return;
  int s,d;
  load_edge(ei, *mode_p, e, E, s, d);
  float2 sv = asx[s];
  float al = leaky(sv.x + a_dst[d], 0.2f);
  float ew = __expf(al);
  atomicAdd(&denom[d], ew);
  atomicAdd(&oacc[d], ew * sv.y);
}

__global__ __launch_bounds__(256) void finalize(
    const float* __restrict__ oacc, const float* __restrict__ denom,
    const float* __restrict__ vcomb, float* __restrict__ out, int N)
{
  int n = blockIdx.x*256+threadIdx.x;
  if (n>=N) return;
  float v = oacc[n] * rcpf(denom[n]) + vcomb[192];
  out[n] = leaky(v, 0.01f);
}

extern "C" void kernel_launch(void* const* d_in, const int* in_sizes, int n_in,
                              void* d_out, int out_size, void* d_ws, size_t ws_size,
                              hipStream_t stream)
{
  const float* x      = (const float*)d_in[0];
  const float* W_ih   = (const float*)d_in[1];
  const float* W_hh   = (const float*)d_in[2];
  const float* b_ih   = (const float*)d_in[3];
  const float* b_hh   = (const float*)d_in[4];
  const float* gat_w  = (const float*)d_in[5];
  const float* att_s  = (const float*)d_in[6];
  const float* att_d  = (const float*)d_in[7];
  const float* gat_b  = (const float*)d_in[8];
  const float* fc_w   = (const float*)d_in[9];
  const float* fc_b   = (const float*)d_in[10];
  const int*   ei     = (const int*)d_in[11];

  const int N = in_sizes[0]/(T_STEPS*F_INP);
  const long long E = in_sizes[11]/2;
  const long long total = E + N;

  float* ws = (float*)d_ws;
  size_t off = 0;
  float2* asx    = (float2*)(ws + off); off += (size_t)2*N;
  float* a_dst   = ws + off; off += (size_t)N;
  float* denom   = ws + off; off += (size_t)N;
  float* oacc    = ws + off; off += (size_t)N;
  float* vcomb   = ws + off; off += 256;
  unsigned* mode = (unsigned*)(ws + off); off += 1;

  gat_setup<<<1,64,0,stream>>>(ei, gat_w, att_s, att_d, fc_w, gat_b, fc_b, vcomb, mode);

  lstm_mfma<<<dim3((N+31)/32), dim3(256), 0, stream>>>(
      x, W_ih, W_hh, b_ih, b_hh, vcomb, asx, a_dst, denom, oacc, N);

  int eb = (int)((total+255)/256);
  edge_pass<<<dim3(eb), dim3(256), 0, stream>>>(ei, mode, asx, a_dst, denom, oacc, E, total);

  finalize<<<dim3((N+255)/256), dim3(256), 0, stream>>>(oacc, denom, vcomb, (float*)d_out, N);
}